// Round 6
// baseline (617.340 us; speedup 1.0000x reference)
//
#include <hip/hip_runtime.h>
#include <stdint.h>
#include <math.h>

typedef short    s16x8  __attribute__((ext_vector_type(8)));
typedef float    f32x4  __attribute__((ext_vector_type(4)));
typedef float    f32x16 __attribute__((ext_vector_type(16)));
typedef uint32_t u32x4  __attribute__((ext_vector_type(4)));
typedef unsigned short u16x4 __attribute__((ext_vector_type(4)));
typedef unsigned short u16x8 __attribute__((ext_vector_type(8)));

__device__ __forceinline__ uint16_t f2bf(float f) {
  union { float f; uint32_t u; } v; v.f = f;
  uint32_t r = v.u + 0x7fffu + ((v.u >> 16) & 1u);
  return (uint16_t)(r >> 16);
}
__device__ __forceinline__ float bf2f(uint16_t h) {
  union { uint32_t u; float f; } v; v.u = ((uint32_t)h) << 16;
  return v.f;
}

// async global->LDS, 16B per lane; LDS dest = wave-uniform base + lane*16
__device__ __forceinline__ void gld16(const void* g, void* l) {
  __builtin_amdgcn_global_load_lds(
      (const __attribute__((address_space(1))) void*)g,
      (__attribute__((address_space(3))) void*)l, 16, 0, 0);
}

// ---------------- K0: x fp32 -> xf bf16 (2048 x 4096); also zeroes rs ----------------
__global__ __launch_bounds__(256) void cvt_x(const float* __restrict__ x,
                                             uint16_t* __restrict__ xf,
                                             float* __restrict__ rs) {
  if (blockIdx.x < 64) rs[blockIdx.x * 256 + threadIdx.x] = 0.f;
  size_t i = ((size_t)blockIdx.x * 256 + threadIdx.x) * 4;
  f32x4 v = *(const f32x4*)(x + i);
  u16x4 o = { f2bf(v.x), f2bf(v.y), f2bf(v.z), f2bf(v.w) };
  *(u16x4*)(xf + i) = o;
}

// ------------- K1: W (3 x H x 4096 x 512 fp32) -> Wt (24 x 512 x 4096 bf16) -------------
// 64(f) x 32(u) tiles; writes are full 16B u16x8 -> coalesced 128B per u-row.
__global__ __launch_bounds__(256) void wtrans(const float* __restrict__ W0,
                                              const float* __restrict__ W1,
                                              const float* __restrict__ W2,
                                              uint16_t* __restrict__ Wt) {
  const int z = blockIdx.z;  // mat*8 + h
  const float* W = (z < 8 ? W0 : (z < 16 ? W1 : W2)) + (size_t)(z & 7) * (4096 * 512);
  const int f0 = blockIdx.x * 64, u0 = blockIdx.y * 32;
  __shared__ float t[64][33];
  const int tid = threadIdx.x;
  {
    const int fi = tid >> 2, uu = (tid & 3) * 8;
    const float* src = W + (size_t)(f0 + fi) * 512 + u0 + uu;
    f32x4 v0 = *(const f32x4*)src;
    f32x4 v1 = *(const f32x4*)(src + 4);
    t[fi][uu] = v0.x; t[fi][uu + 1] = v0.y; t[fi][uu + 2] = v0.z; t[fi][uu + 3] = v0.w;
    t[fi][uu + 4] = v1.x; t[fi][uu + 5] = v1.y; t[fi][uu + 6] = v1.z; t[fi][uu + 7] = v1.w;
  }
  __syncthreads();
  {
    const int uo = tid >> 3, fo = (tid & 7) * 8;
    u16x8 o = { f2bf(t[fo][uo]),     f2bf(t[fo + 1][uo]), f2bf(t[fo + 2][uo]),
                f2bf(t[fo + 3][uo]), f2bf(t[fo + 4][uo]), f2bf(t[fo + 5][uo]),
                f2bf(t[fo + 6][uo]), f2bf(t[fo + 7][uo]) };
    *(u16x8*)&Wt[((size_t)z * 512 + u0 + uo) * 4096 + f0 + fo] = o;
  }
}

// ------------- 128x128-tile bf16 B^T GEMM, BK=64, 32x32x16 MFMA -------------
// C[m][n] = sum_k A[m][k]*B[n][k]; A: M x K, B: N x K row-major bf16 (k-contiguous).
// 4 waves, 64x64 per wave = 2x2 frags of 32x32 (f32x16 acc, 64 AGPR).
// LDS row stride 64 elems = 128 B; XOR swizzle slot(r,s) = s ^ (r&7): staging and
// b128 fragment reads both uniform over bank groups (0 conflicts, verified R3/R5).
// A-frag: lane holds A[m=lane&31][k=(lane>>5)*8 + j]; C/D: col=lane&31,
// row = (reg&3) + 8*(reg>>2) + 4*(lane>>5)  [m74/m101].
// MODE 4: z<16 -> bf16 rows into C0 + z*2^20 (ldc 512) [q|k];
//         z>=16 -> bf16 TRANSPOSED into C1 + (z-16)*2^20 (ldc 2048) [vt]
// MODE 2: bf16 exp2(acc*scale-c) into C0 + z*2^22 (ldc 2048) + atomic rowsum -> rs
// MODE 3: split-K=2: z' = z + 8*kh; fp32 acc/rs[row] into (kh? C1 : C0) + z*2^20
template <int MODE>
__global__ __launch_bounds__(256, 4) void gemm_bt(
    const uint16_t* __restrict__ A, size_t sAz,
    const uint16_t* __restrict__ B, size_t sBz,
    void* __restrict__ C0, void* __restrict__ C1,
    int K, float scale, float* __restrict__ rs) {
  const int tid = threadIdx.x;
  const int wave = tid >> 6, lane = tid & 63;
  const int l31 = lane & 31, h = lane >> 5;
  const int wrow = (wave >> 1) * 64, wcol = (wave & 1) * 64;
  const int m0 = blockIdx.y * 128, n0 = blockIdx.x * 128;
  int z = blockIdx.z, kh = 0, Kloop = K;
  if (MODE == 3) { kh = z >> 3; z &= 7; Kloop = K >> 1; }
  A += (size_t)z * sAz + (size_t)kh * Kloop;
  B += (size_t)z * sBz + (size_t)kh * Kloop;

  __shared__ __align__(16) uint16_t lA[128 * 64];
  __shared__ __align__(16) uint16_t lB[128 * 64];

  f32x16 acc[2][2];
#pragma unroll
  for (int i = 0; i < 2; i++)
#pragma unroll
    for (int j = 0; j < 2; j++)
#pragma unroll
      for (int r = 0; r < 16; r++) acc[i][j][r] = 0.f;

  // staging: per gld16 one wave covers 8 rows x 8 chunks (128 B/row).
  // lane l -> row rs0 + (l>>3), slot l&7, global chunk (l&7) ^ ((l>>3)&7)
  const int lrow = lane >> 3;
  const int cs = ((lane & 7) ^ (lrow & 7)) * 8;  // elems
  const int rs0 = wave * 8;
  const uint16_t* gA = A + (size_t)(m0 + rs0 + lrow) * K + cs;
  const uint16_t* gB = B + (size_t)(n0 + rs0 + lrow) * K + cs;
  const size_t row32 = (size_t)32 * K;
  uint16_t* sA = &lA[rs0 * 64];
  uint16_t* sB = &lB[rs0 * 64];

  for (int k0 = 0; k0 < Kloop; k0 += 64) {
    __syncthreads();  // prev-iter LDS reads complete before overwrite
#pragma unroll
    for (int g = 0; g < 4; g++) {
      gld16(gA + g * row32, sA + g * 2048);
      gld16(gB + g * row32, sB + g * 2048);
    }
    gA += 64; gB += 64;
    __syncthreads();  // drains vmcnt -> staged data visible
#pragma unroll
    for (int s = 0; s < 4; s++) {  // k-steps of 16
      const int fsw = (((s * 2 + h) ^ (lane & 7)) * 8);
      s16x8 af[2], bfr[2];
#pragma unroll
      for (int i = 0; i < 2; i++)
        af[i] = *(const s16x8*)&lA[(wrow + i * 32 + l31) * 64 + fsw];
#pragma unroll
      for (int j = 0; j < 2; j++)
        bfr[j] = *(const s16x8*)&lB[(wcol + j * 32 + l31) * 64 + fsw];
#pragma unroll
      for (int i = 0; i < 2; i++)
#pragma unroll
        for (int j = 0; j < 2; j++)
          acc[i][j] = __builtin_amdgcn_mfma_f32_32x32x16_bf16(af[i], bfr[j], acc[i][j], 0, 0, 0);
    }
  }

  // C/D: col = n0+wcol+j*32+l31; row = m0+wrow+i*32 + 4*h + 8*g + r (g=reg>>2,r=reg&3)
  if (MODE == 4) {
    if (z < 16) {
      uint16_t* C = (uint16_t*)C0 + ((size_t)z << 20);
#pragma unroll
      for (int i = 0; i < 2; i++) {
        const int rb = m0 + wrow + i * 32 + 4 * h;
#pragma unroll
        for (int j = 0; j < 2; j++) {
          const int col = n0 + wcol + j * 32 + l31;
#pragma unroll
          for (int g = 0; g < 4; g++)
#pragma unroll
            for (int r = 0; r < 4; r++)
              C[(size_t)(rb + 8 * g + r) * 512 + col] = f2bf(acc[i][j][g * 4 + r]);
        }
      }
    } else {
      uint16_t* C = (uint16_t*)C1 + ((size_t)(z - 16) << 20);
#pragma unroll
      for (int i = 0; i < 2; i++) {
        const int rb = m0 + wrow + i * 32 + 4 * h;
#pragma unroll
        for (int j = 0; j < 2; j++) {
          const int col = n0 + wcol + j * 32 + l31;
#pragma unroll
          for (int g = 0; g < 4; g++) {
            u16x4 o = { f2bf(acc[i][j][g * 4]),     f2bf(acc[i][j][g * 4 + 1]),
                        f2bf(acc[i][j][g * 4 + 2]), f2bf(acc[i][j][g * 4 + 3]) };
            *(u16x4*)&C[(size_t)col * 2048 + rb + 8 * g] = o;
          }
        }
      }
    }
  } else if (MODE == 2) {
    uint16_t* C = (uint16_t*)C0 + ((size_t)z << 22);
    float* rz = rs + (z << 11);
#pragma unroll
    for (int i = 0; i < 2; i++) {
      const int rb = m0 + wrow + i * 32 + 4 * h;
#pragma unroll
      for (int j = 0; j < 2; j++) {
        const int col = n0 + wcol + j * 32 + l31;
#pragma unroll
        for (int g = 0; g < 4; g++)
#pragma unroll
          for (int r = 0; r < 4; r++) {
            // exp(s*scale-30) == exp2(s*scale*log2e - 30*log2e)
            float e = exp2f(fmaf(acc[i][j][g * 4 + r], scale, -43.2808512f));
            uint16_t hb = f2bf(e);
            C[(size_t)(rb + 8 * g + r) * 2048 + col] = hb;
            acc[i][j][g * 4 + r] = bf2f(hb);  // keep rounded value for rowsum
          }
      }
    }
    // row sums: reduce over the 32 columns (lanes l31) of each half-wave
#pragma unroll
    for (int i = 0; i < 2; i++) {
      const int rb = m0 + wrow + i * 32 + 4 * h;
#pragma unroll
      for (int g = 0; g < 4; g++)
#pragma unroll
        for (int r = 0; r < 4; r++) {
          float s = acc[i][0][g * 4 + r] + acc[i][1][g * 4 + r];
          s += __shfl_xor(s, 1);
          s += __shfl_xor(s, 2);
          s += __shfl_xor(s, 4);
          s += __shfl_xor(s, 8);
          s += __shfl_xor(s, 16);
          if (l31 == 0) atomicAdd(&rz[rb + 8 * g + r], s);
        }
    }
  } else {  // MODE 3 (split-K partial, scaled by 1/rowsum)
    float* C = (float*)(kh ? C1 : C0) + ((size_t)z << 20);
    const float* rz = rs + (z << 11);
#pragma unroll
    for (int i = 0; i < 2; i++) {
      const int rb = m0 + wrow + i * 32 + 4 * h;
#pragma unroll
      for (int g = 0; g < 4; g++) {
        f32x4 rv = *(const f32x4*)&rz[rb + 8 * g];
#pragma unroll
        for (int j = 0; j < 2; j++) {
          const int col = n0 + wcol + j * 32 + l31;
#pragma unroll
          for (int r = 0; r < 4; r++)
            C[(size_t)(rb + 8 * g + r) * 512 + col] = acc[i][j][g * 4 + r] / rv[r];
        }
      }
    }
  }
}

// ------------- K6: out = concat(av0+av1) @ Wo (32x32) -------------
__global__ __launch_bounds__(256) void out_proj(const float* __restrict__ av0,
                                                const float* __restrict__ av1,
                                                const float* __restrict__ Wo,
                                                float* __restrict__ out) {
  __shared__ float lw[1024];
  const int tid = threadIdx.x;
#pragma unroll
  for (int i = 0; i < 4; i++) lw[tid + i * 256] = Wo[tid + i * 256];
  __syncthreads();
  const int p = blockIdx.x * 256 + tid;  // b*128 + n
  const int b = p >> 7, n = p & 127;
  float c[32];
#pragma unroll
  for (int hh = 0; hh < 8; hh++) {
    size_t idx = ((size_t)hh * 2048 + b) * 512 + n * 4;
    f32x4 v = *(const f32x4*)(av0 + idx);
    f32x4 w = *(const f32x4*)(av1 + idx);
    c[hh * 4] = v.x + w.x; c[hh * 4 + 1] = v.y + w.y;
    c[hh * 4 + 2] = v.z + w.z; c[hh * 4 + 3] = v.w + w.w;
  }
  float o[32];
#pragma unroll
  for (int d = 0; d < 32; d++) o[d] = 0.f;
#pragma unroll
  for (int j = 0; j < 32; j++) {
    float cj = c[j];
#pragma unroll
    for (int d = 0; d < 32; d++) o[d] = fmaf(cj, lw[j * 32 + d], o[d]);
  }
  float* dst = out + (size_t)p * 32;
#pragma unroll
  for (int i = 0; i < 8; i++) {
    f32x4 v = { o[i * 4], o[i * 4 + 1], o[i * 4 + 2], o[i * 4 + 3] };
    *(f32x4*)(dst + i * 4) = v;
  }
}

extern "C" void kernel_launch(void* const* d_in, const int* in_sizes, int n_in,
                              void* d_out, int out_size, void* d_ws, size_t ws_size,
                              hipStream_t stream) {
  const float* x  = (const float*)d_in[0];
  const float* Wq = (const float*)d_in[1];
  const float* Wk = (const float*)d_in[2];
  const float* Wv = (const float*)d_in[3];
  const float* Wo = (const float*)d_in[4];
  float* out = (float*)d_out;

  // ws layout (bytes), total 167,837,696:
  //   [0, 100663296): Wt bf16 (24 x 512 x 4096) -- dead after projections;
  //     then: P_u bf16 (8x2048x2048) at 0, av0 fp32 (8x2048x512) at 67108864
  //   [100663296): xf bf16, [117440512): q bf16, [134217728): k bf16
  //     (q,k dead after QK^T -> av1 fp32 (33.5 MB) overlays them during PV)
  //   [150994944): vt bf16, [167772160): rs fp32 (8x2048)
  uint8_t* ws = (uint8_t*)d_ws;
  uint16_t* Wt  = (uint16_t*)(ws);
  uint16_t* P   = (uint16_t*)(ws);
  float*    av0 = (float*)(ws + 67108864);
  uint16_t* xf  = (uint16_t*)(ws + 100663296);
  uint16_t* q   = (uint16_t*)(ws + 117440512);
  float*    av1 = (float*)(ws + 117440512);
  uint16_t* vt  = (uint16_t*)(ws + 150994944);
  float*    rs  = (float*)(ws + 167772160);

  const size_t WtH = (size_t)512 * 4096;  // per-head Wt elements
  // qk^T scale folded with log2(e) for exp2: 32^-0.5 * 1.4426950408889634
  const float scale2 = 0.17677669529663687f * 1.4426950408889634f;

  cvt_x<<<8192, 256, 0, stream>>>(x, xf, rs);
  wtrans<<<dim3(64, 16, 24), 256, 0, stream>>>(Wq, Wk, Wv, Wt);

  // fused q|k|v projections: M=2048, N=512, K=4096, z=0..23
  gemm_bt<4><<<dim3(4, 16, 24), 256, 0, stream>>>(
      xf, 0, Wt, WtH, q, vt, 4096, 0.f, nullptr);

  // P_u = exp2(q k^T * scale2 - 30*log2e) + fused rowsum: M=N=2048, K=512
  gemm_bt<2><<<dim3(16, 16, 8), 256, 0, stream>>>(
      q, (size_t)2048 * 512, q + (size_t)8 * 2048 * 512, (size_t)2048 * 512,
      P, nullptr, 512, scale2, rs);

  // av = (P_u @ v) / rowsum, split-K=2 (z = head + 8*khalf): M=2048, N=512, K=2048
  gemm_bt<3><<<dim3(4, 16, 16), 256, 0, stream>>>(
      P, (size_t)2048 * 2048, vt, (size_t)512 * 2048,
      av0, av1, 2048, 0.f, rs);

  out_proj<<<1024, 256, 0, stream>>>(av0, av1, Wo, out);
}

// Round 7
// 565.071 us; speedup vs baseline: 1.0925x; 1.0925x over previous
//
#include <hip/hip_runtime.h>
#include <stdint.h>
#include <math.h>

typedef short    s16x8 __attribute__((ext_vector_type(8)));
typedef float    f32x4 __attribute__((ext_vector_type(4)));
typedef uint32_t u32x4 __attribute__((ext_vector_type(4)));
typedef unsigned short u16x4 __attribute__((ext_vector_type(4)));
typedef unsigned short u16x8 __attribute__((ext_vector_type(8)));

__device__ __forceinline__ uint16_t f2bf(float f) {
  union { float f; uint32_t u; } v; v.f = f;
  uint32_t r = v.u + 0x7fffu + ((v.u >> 16) & 1u);
  return (uint16_t)(r >> 16);
}
__device__ __forceinline__ float bf2f(uint16_t h) {
  union { uint32_t u; float f; } v; v.u = ((uint32_t)h) << 16;
  return v.f;
}

// async global->LDS, 16B per lane; LDS dest = wave-uniform base + lane*16
__device__ __forceinline__ void gld16(const void* g, void* l) {
  __builtin_amdgcn_global_load_lds(
      (const __attribute__((address_space(1))) void*)g,
      (__attribute__((address_space(3))) void*)l, 16, 0, 0);
}

// ---------------- K0: x fp32 -> xf bf16 (2048 x 4096); also zeroes rs ----------------
__global__ __launch_bounds__(256) void cvt_x(const float* __restrict__ x,
                                             uint16_t* __restrict__ xf,
                                             float* __restrict__ rs) {
  if (blockIdx.x < 64) rs[blockIdx.x * 256 + threadIdx.x] = 0.f;
  size_t i = ((size_t)blockIdx.x * 256 + threadIdx.x) * 4;
  f32x4 v = *(const f32x4*)(x + i);
  u16x4 o = { f2bf(v.x), f2bf(v.y), f2bf(v.z), f2bf(v.w) };
  *(u16x4*)(xf + i) = o;
}

// ------------- K1: W (3 x H x 4096 x 512 fp32) -> Wt (24 x 512 x 4096 bf16) -------------
// 64(f) x 32(u) tiles; writes are full 16B u16x8 -> coalesced 128B per u-row.
__global__ __launch_bounds__(256) void wtrans(const float* __restrict__ W0,
                                              const float* __restrict__ W1,
                                              const float* __restrict__ W2,
                                              uint16_t* __restrict__ Wt) {
  const int z = blockIdx.z;  // mat*8 + h
  const float* W = (z < 8 ? W0 : (z < 16 ? W1 : W2)) + (size_t)(z & 7) * (4096 * 512);
  const int f0 = blockIdx.x * 64, u0 = blockIdx.y * 32;
  __shared__ float t[64][33];
  const int tid = threadIdx.x;
  {
    const int fi = tid >> 2, uu = (tid & 3) * 8;
    const float* src = W + (size_t)(f0 + fi) * 512 + u0 + uu;
    f32x4 v0 = *(const f32x4*)src;
    f32x4 v1 = *(const f32x4*)(src + 4);
    t[fi][uu] = v0.x; t[fi][uu + 1] = v0.y; t[fi][uu + 2] = v0.z; t[fi][uu + 3] = v0.w;
    t[fi][uu + 4] = v1.x; t[fi][uu + 5] = v1.y; t[fi][uu + 6] = v1.z; t[fi][uu + 7] = v1.w;
  }
  __syncthreads();
  {
    const int uo = tid >> 3, fo = (tid & 7) * 8;
    u16x8 o = { f2bf(t[fo][uo]),     f2bf(t[fo + 1][uo]), f2bf(t[fo + 2][uo]),
                f2bf(t[fo + 3][uo]), f2bf(t[fo + 4][uo]), f2bf(t[fo + 5][uo]),
                f2bf(t[fo + 6][uo]), f2bf(t[fo + 7][uo]) };
    *(u16x8*)&Wt[((size_t)z * 512 + u0 + uo) * 4096 + f0 + fo] = o;
  }
}

// ------------- 128x128-tile bf16 B^T GEMM, BK=64, 16x16x32 MFMA -------------
// (R5 core: empirically conflict-free fragment pattern -- do not change the
//  l16/quad read geometry; the 32x32 l31/h geometry measured 4-way conflicts.)
// C[m][n] = sum_k A[m][k]*B[n][k]; A: M x K, B: N x K row-major bf16 (k-contiguous).
// LDS row stride 64 elems = 128 B; XOR swizzle slot(r,s) = s ^ (r&7).
// MODE 4: z<16 -> bf16 rows into C0 + z*2^20 (ldc 512) [q|k];
//         z>=16 -> bf16 TRANSPOSED into C1 + (z-16)*2^20 (ldc 2048) [vt]
// MODE 2: bf16 exp2(acc*scale-c) into C0 + z*2^22 (ldc 2048) + atomic rowsum -> rs
// MODE 3: split-K=2 (z' = z + 8*kh): fp32 acc/rs[row] into (kh? C1 : C0) + z*2^20
template <int MODE>
__global__ __launch_bounds__(256, 4) void gemm_bt(
    const uint16_t* __restrict__ A, size_t sAz,
    const uint16_t* __restrict__ B, size_t sBz,
    void* __restrict__ C0, void* __restrict__ C1,
    int K, float scale, float* __restrict__ rs) {
  const int tid = threadIdx.x;
  const int wave = tid >> 6, lane = tid & 63;
  const int quad = lane >> 4, l16 = lane & 15;
  const int wrow = (wave >> 1) * 64, wcol = (wave & 1) * 64;
  const int m0 = blockIdx.y * 128, n0 = blockIdx.x * 128;
  int z = blockIdx.z, kh = 0, Kloop = K;
  if (MODE == 3) { kh = z >> 3; z &= 7; Kloop = K >> 1; }
  A += (size_t)z * sAz + (size_t)kh * Kloop;
  B += (size_t)z * sBz + (size_t)kh * Kloop;

  __shared__ __align__(16) uint16_t lA[128 * 64];
  __shared__ __align__(16) uint16_t lB[128 * 64];

  f32x4 acc[4][4];
#pragma unroll
  for (int i = 0; i < 4; i++)
#pragma unroll
    for (int j = 0; j < 4; j++) acc[i][j] = f32x4{0.f, 0.f, 0.f, 0.f};

  // staging: per gld16 one wave covers 8 rows x 8 chunks (128 B/row).
  // lane l -> row rs0 + (l>>3), slot l&7, global chunk (l&7) ^ ((l>>3)&7)
  const int lrow = lane >> 3;
  const int cs = ((lane & 7) ^ (lrow & 7)) * 8;  // elems
  const int rs0 = wave * 8;
  const uint16_t* gA = A + (size_t)(m0 + rs0 + lrow) * K + cs;
  const uint16_t* gB = B + (size_t)(n0 + rs0 + lrow) * K + cs;
  const size_t row32 = (size_t)32 * K;
  uint16_t* sA = &lA[rs0 * 64];
  uint16_t* sB = &lB[rs0 * 64];

  for (int k0 = 0; k0 < Kloop; k0 += 64) {
    __syncthreads();  // prev-iter LDS reads complete before overwrite
#pragma unroll
    for (int g = 0; g < 4; g++) {
      gld16(gA + g * row32, sA + g * 2048);
      gld16(gB + g * row32, sB + g * 2048);
    }
    gA += 64; gB += 64;
    __syncthreads();  // drains vmcnt -> staged data visible
#pragma unroll
    for (int h = 0; h < 2; h++) {
      s16x8 af[4], bfr[4];
      const int fsw = (((h * 4 + quad) ^ (l16 & 7)) * 8);
#pragma unroll
      for (int i = 0; i < 4; i++)
        af[i] = *(const s16x8*)&lA[(wrow + i * 16 + l16) * 64 + fsw];
#pragma unroll
      for (int j = 0; j < 4; j++)
        bfr[j] = *(const s16x8*)&lB[(wcol + j * 16 + l16) * 64 + fsw];
#pragma unroll
      for (int i = 0; i < 4; i++)
#pragma unroll
        for (int j = 0; j < 4; j++)
          acc[i][j] = __builtin_amdgcn_mfma_f32_16x16x32_bf16(af[i], bfr[j], acc[i][j], 0, 0, 0);
    }
  }

  // C/D layout (verified m89/m91): col = lane&15, row = quad*4 + reg
  const int mb = m0 + wrow + quad * 4;
  const int nb = n0 + wcol + l16;
  if (MODE == 4) {
    if (z < 16) {
      uint16_t* C = (uint16_t*)C0 + ((size_t)z << 20);
#pragma unroll
      for (int i = 0; i < 4; i++)
#pragma unroll
        for (int j = 0; j < 4; j++)
#pragma unroll
          for (int r = 0; r < 4; r++)
            C[(size_t)(mb + i * 16 + r) * 512 + (nb + j * 16)] = f2bf(acc[i][j][r]);
    } else {
      uint16_t* C = (uint16_t*)C1 + ((size_t)(z - 16) << 20);
#pragma unroll
      for (int i = 0; i < 4; i++)
#pragma unroll
        for (int j = 0; j < 4; j++) {
          u16x4 o = { f2bf(acc[i][j][0]), f2bf(acc[i][j][1]),
                      f2bf(acc[i][j][2]), f2bf(acc[i][j][3]) };
          *(u16x4*)&C[(size_t)(nb + j * 16) * 2048 + (mb + i * 16)] = o;
        }
    }
  } else if (MODE == 2) {
    uint16_t* C = (uint16_t*)C0 + ((size_t)z << 22);
    float* rz = rs + (z << 11);
    float si[4][4];
#pragma unroll
    for (int i = 0; i < 4; i++)
#pragma unroll
      for (int r = 0; r < 4; r++) si[i][r] = 0.f;
#pragma unroll
    for (int i = 0; i < 4; i++)
#pragma unroll
      for (int j = 0; j < 4; j++)
#pragma unroll
        for (int r = 0; r < 4; r++) {
          // exp(s*scale-30) == exp2(s*scale*log2e - 30*log2e)
          float e = exp2f(fmaf(acc[i][j][r], scale, -43.2808512f));
          uint16_t hb = f2bf(e);
          C[(size_t)(mb + i * 16 + r) * 2048 + (nb + j * 16)] = hb;
          si[i][r] += bf2f(hb);  // sum the rounded values (matches stored P)
        }
    // reduce over the 16 l16 lanes (64 columns of this wave)
#pragma unroll
    for (int i = 0; i < 4; i++)
#pragma unroll
      for (int r = 0; r < 4; r++) {
        float s = si[i][r];
        s += __shfl_xor(s, 1);
        s += __shfl_xor(s, 2);
        s += __shfl_xor(s, 4);
        s += __shfl_xor(s, 8);
        si[i][r] = s;
      }
    if (l16 == 0) {
#pragma unroll
      for (int i = 0; i < 4; i++)
#pragma unroll
        for (int r = 0; r < 4; r++)
          atomicAdd(&rz[mb + i * 16 + r], si[i][r]);
    }
  } else {  // MODE 3 (split-K partial, scaled by 1/rowsum)
    float* C = (float*)(kh ? C1 : C0) + ((size_t)z << 20);
    const float* rz = rs + (z << 11);
#pragma unroll
    for (int i = 0; i < 4; i++)
#pragma unroll
      for (int r = 0; r < 4; r++) {
        float w = 1.0f / rz[mb + i * 16 + r];
#pragma unroll
        for (int j = 0; j < 4; j++)
          C[(size_t)(mb + i * 16 + r) * 512 + (nb + j * 16)] = acc[i][j][r] * w;
      }
  }
}

// ------------- K6: out = concat(av0+av1) @ Wo (32x32) -------------
__global__ __launch_bounds__(256) void out_proj(const float* __restrict__ av0,
                                                const float* __restrict__ av1,
                                                const float* __restrict__ Wo,
                                                float* __restrict__ out) {
  __shared__ float lw[1024];
  const int tid = threadIdx.x;
#pragma unroll
  for (int i = 0; i < 4; i++) lw[tid + i * 256] = Wo[tid + i * 256];
  __syncthreads();
  const int p = blockIdx.x * 256 + tid;  // b*128 + n
  const int b = p >> 7, n = p & 127;
  float c[32];
#pragma unroll
  for (int hh = 0; hh < 8; hh++) {
    size_t idx = ((size_t)hh * 2048 + b) * 512 + n * 4;
    f32x4 v = *(const f32x4*)(av0 + idx);
    f32x4 w = *(const f32x4*)(av1 + idx);
    c[hh * 4] = v.x + w.x; c[hh * 4 + 1] = v.y + w.y;
    c[hh * 4 + 2] = v.z + w.z; c[hh * 4 + 3] = v.w + w.w;
  }
  float o[32];
#pragma unroll
  for (int d = 0; d < 32; d++) o[d] = 0.f;
#pragma unroll
  for (int j = 0; j < 32; j++) {
    float cj = c[j];
#pragma unroll
    for (int d = 0; d < 32; d++) o[d] = fmaf(cj, lw[j * 32 + d], o[d]);
  }
  float* dst = out + (size_t)p * 32;
#pragma unroll
  for (int i = 0; i < 8; i++) {
    f32x4 v = { o[i * 4], o[i * 4 + 1], o[i * 4 + 2], o[i * 4 + 3] };
    *(f32x4*)(dst + i * 4) = v;
  }
}

extern "C" void kernel_launch(void* const* d_in, const int* in_sizes, int n_in,
                              void* d_out, int out_size, void* d_ws, size_t ws_size,
                              hipStream_t stream) {
  const float* x  = (const float*)d_in[0];
  const float* Wq = (const float*)d_in[1];
  const float* Wk = (const float*)d_in[2];
  const float* Wv = (const float*)d_in[3];
  const float* Wo = (const float*)d_in[4];
  float* out = (float*)d_out;

  // ws layout (bytes), total 167,837,696:
  //   [0, 100663296): Wt bf16 (24 x 512 x 4096) -- dead after projections;
  //     then: P_u bf16 (8x2048x2048) at 0, av0 fp32 (8x2048x512) at 67108864
  //   [100663296): xf bf16, [117440512): q bf16, [134217728): k bf16
  //     (q,k dead after QK^T -> av1 fp32 (33.5 MB) overlays them during PV)
  //   [150994944): vt bf16, [167772160): rs fp32 (8x2048)
  uint8_t* ws = (uint8_t*)d_ws;
  uint16_t* Wt  = (uint16_t*)(ws);
  uint16_t* P   = (uint16_t*)(ws);
  float*    av0 = (float*)(ws + 67108864);
  uint16_t* xf  = (uint16_t*)(ws + 100663296);
  uint16_t* q   = (uint16_t*)(ws + 117440512);
  float*    av1 = (float*)(ws + 117440512);
  uint16_t* vt  = (uint16_t*)(ws + 150994944);
  float*    rs  = (float*)(ws + 167772160);

  const size_t WtH = (size_t)512 * 4096;  // per-head Wt elements
  // qk^T scale folded with log2(e) for exp2: 32^-0.5 * 1.4426950408889634
  const float scale2 = 0.17677669529663687f * 1.4426950408889634f;

  cvt_x<<<8192, 256, 0, stream>>>(x, xf, rs);
  wtrans<<<dim3(64, 16, 24), 256, 0, stream>>>(Wq, Wk, Wv, Wt);

  // fused q|k|v projections: M=2048, N=512, K=4096, z=0..23
  gemm_bt<4><<<dim3(4, 16, 24), 256, 0, stream>>>(
      xf, 0, Wt, WtH, q, vt, 4096, 0.f, nullptr);

  // P_u = exp2(q k^T * scale2 - 30*log2e) + fused rowsum: M=N=2048, K=512
  gemm_bt<2><<<dim3(16, 16, 8), 256, 0, stream>>>(
      q, (size_t)2048 * 512, q + (size_t)8 * 2048 * 512, (size_t)2048 * 512,
      P, nullptr, 512, scale2, rs);

  // av = (P_u @ v) / rowsum, split-K=2 (z = head + 8*khalf): M=2048, N=512, K=2048
  gemm_bt<3><<<dim3(4, 16, 16), 256, 0, stream>>>(
      P, (size_t)2048 * 2048, vt, (size_t)512 * 2048,
      av0, av1, 2048, 0.f, rs);

  out_proj<<<1024, 256, 0, stream>>>(av0, av1, Wo, out);
}